// Round 1
// 945.742 us; speedup vs baseline: 1.0364x; 1.0364x over previous
//
#include <hip/hip_runtime.h>

#define N_NODES 50000
#define E_EDGES 800000

// ============================ CSR build =====================================
__global__ __launch_bounds__(256) void k_hist(
    const int* __restrict__ ei, int* __restrict__ cnt)
{
    const int e = blockIdx.x * 256 + threadIdx.x;
    if (e < E_EDGES) atomicAdd(&cnt[ei[E_EDGES + e]], 1);
}

// single block, 1024 threads: exclusive prefix over cnt -> rowptr, cursor
__global__ __launch_bounds__(1024) void k_scan(
    const int* __restrict__ cnt, int* __restrict__ rowptr, int* __restrict__ cursor)
{
    __shared__ int part[1024];
    const int tid = threadIdx.x;
    const int CH = 49;                      // 1024*49 >= 50000
    const int base = tid * CH;
    int sum = 0;
    for (int c = 0; c < CH; ++c) {
        const int i = base + c;
        if (i < N_NODES) sum += cnt[i];
    }
    part[tid] = sum;
    __syncthreads();
    for (int off = 1; off < 1024; off <<= 1) {
        int v = part[tid];
        int u = (tid >= off) ? part[tid - off] : 0;
        __syncthreads();
        part[tid] = v + u;
        __syncthreads();
    }
    int run = (tid > 0) ? part[tid - 1] : 0;
    for (int c = 0; c < CH; ++c) {
        const int i = base + c;
        if (i < N_NODES) {
            rowptr[i] = run;
            cursor[i] = run;
            run += cnt[i];
        }
    }
    if (tid == 1023) rowptr[N_NODES] = part[1023];
}

__global__ __launch_bounds__(256) void k_scatter(
    const int* __restrict__ ei, int* __restrict__ cursor, int2* __restrict__ pairs)
{
    const int e = blockIdx.x * 256 + threadIdx.x;
    if (e < E_EDGES) {
        const int dst = ei[E_EDGES + e];
        const int pos = atomicAdd(&cursor[dst], 1);
        pairs[pos] = make_int2(ei[e], e);
    }
}

// ============ CSR-order edge-attr pre-scale (kills gather deps) =============
// eaw[pos][k] = ew[eid] * eattr[eid][k]  (layer-independent), srcs[pos] = src.
// 4 threads per position: eattr read is a coalesced 64B quad per edge,
// eaw write fully coalesced.
__global__ __launch_bounds__(256) void k_prep(
    const int2* __restrict__ pairs, const float* __restrict__ eattr,
    const float* __restrict__ ew, float* __restrict__ eaw, int* __restrict__ srcs)
{
    const int t = blockIdx.x * 256 + threadIdx.x;
    const int pos = t >> 2;
    if (pos >= E_EDGES) return;
    const int q = t & 3;
    const int2 p = pairs[pos];
    if (q == 0) srcs[pos] = p.x;
    const float w = ew[p.y];
    const float4 a = *((const float4*)(eattr + (size_t)p.y * 16) + q);
    *((float4*)(eaw + (size_t)pos * 16) + q) =
        make_float4(a.x * w, a.y * w, a.z * w, a.w * w);
}

// ===================== Edge layer 1 (CSR gather, 16->64) ====================
// out[v][d] = x[v][d] + sum_{e: dst=v} relu( x[src][d] + (eaw_e . We1[d]) + be1[d] )
// eaw is CSR-ordered: its addresses are induction-known (no load->load dep).
// src broadcast via v_readlane (SGPR base for the h gather, no bpermute).
__global__ __launch_bounds__(256, 4) void k_edge1(
    const int* __restrict__ rp, const int* __restrict__ srcs,
    const float* __restrict__ eaw,
    const float* __restrict__ We1, const float* __restrict__ be1,
    const float* __restrict__ x, float* __restrict__ out)
{
    const int lane = threadIdx.x & 63;
    const int node = blockIdx.x * 4 + (threadIdx.x >> 6);
    if (node >= N_NODES) return;

    float wr[16];
#pragma unroll
    for (int k = 0; k < 16; ++k) wr[k] = We1[lane * 16 + k];
    const float bias = be1[lane];

    const int beg = rp[node], end = rp[node + 1];
    float acc = 0.f;

    for (int c = beg; c < end; c += 64) {
        const int n = end - c < 64 ? end - c : 64;   // uniform per wave
        const int sl = srcs[c + (lane < n ? lane : 0)];  // coalesced chunk preload
#pragma unroll 8
        for (int j = 0; j < n; ++j) {
            const int src = __builtin_amdgcn_readlane(sl, j);
            const float hv = x[(size_t)src * 64 + lane];
            const float4* ea = (const float4*)(eaw + (size_t)(c + j) * 16);
            const float4 a0 = ea[0], a1 = ea[1], a2 = ea[2], a3 = ea[3];
            float d0 = fmaf(a0.x, wr[0], fmaf(a0.y, wr[1], bias));
            float d1 = fmaf(a0.z, wr[2], a0.w * wr[3]);
            float d2 = fmaf(a1.x, wr[4], a1.y * wr[5]);
            float d3 = fmaf(a1.z, wr[6], a1.w * wr[7]);
            float d4 = fmaf(a2.x, wr[8], a2.y * wr[9]);
            float d5 = fmaf(a2.z, wr[10], a2.w * wr[11]);
            float d6 = fmaf(a3.x, wr[12], a3.y * wr[13]);
            float d7 = fmaf(a3.z, wr[14], a3.w * wr[15]);
            const float dot = ((d0 + d1) + (d2 + d3)) + ((d4 + d5) + (d6 + d7));
            acc += fmaxf(hv + dot, 0.f);
        }
    }
    out[(size_t)node * 64 + lane] = x[(size_t)node * 64 + lane] + acc;
}

// ===================== Edge layer 2 (CSR gather, 16->128) ===================
// Lane owns dims (2*lane, 2*lane+1); h-row gather one dwordx2 per lane.
__global__ __launch_bounds__(256, 4) void k_edge2(
    const int* __restrict__ rp, const int* __restrict__ srcs,
    const float* __restrict__ eaw,
    const float* __restrict__ We2, const float* __restrict__ be2,
    const float* __restrict__ h, float* __restrict__ out)
{
    const int lane = threadIdx.x & 63;
    const int node = blockIdx.x * 4 + (threadIdx.x >> 6);
    if (node >= N_NODES) return;

    const int dA = 2 * lane;
    float wrA[16], wrB[16];
#pragma unroll
    for (int k = 0; k < 16; ++k) wrA[k] = We2[dA * 16 + k];
#pragma unroll
    for (int k = 0; k < 16; ++k) wrB[k] = We2[(dA + 1) * 16 + k];
    const float biasA = be2[dA];
    const float biasB = be2[dA + 1];

    const int beg = rp[node], end = rp[node + 1];
    float accA = 0.f, accB = 0.f;

    for (int c = beg; c < end; c += 64) {
        const int n = end - c < 64 ? end - c : 64;
        const int sl = srcs[c + (lane < n ? lane : 0)];
#pragma unroll 4
        for (int j = 0; j < n; ++j) {
            const int src = __builtin_amdgcn_readlane(sl, j);
            const float2 hv = *(const float2*)(h + (size_t)src * 128 + dA);
            const float4* ea = (const float4*)(eaw + (size_t)(c + j) * 16);
            const float4 a0 = ea[0], a1 = ea[1], a2 = ea[2], a3 = ea[3];
            float p0 = fmaf(a0.x, wrA[0], fmaf(a0.y, wrA[1], biasA));
            float p1 = fmaf(a0.z, wrA[2], a0.w * wrA[3]);
            float p2 = fmaf(a1.x, wrA[4], a1.y * wrA[5]);
            float p3 = fmaf(a1.z, wrA[6], a1.w * wrA[7]);
            float p4 = fmaf(a2.x, wrA[8], a2.y * wrA[9]);
            float p5 = fmaf(a2.z, wrA[10], a2.w * wrA[11]);
            float p6 = fmaf(a3.x, wrA[12], a3.y * wrA[13]);
            float p7 = fmaf(a3.z, wrA[14], a3.w * wrA[15]);
            const float dotA = ((p0 + p1) + (p2 + p3)) + ((p4 + p5) + (p6 + p7));
            float q0 = fmaf(a0.x, wrB[0], fmaf(a0.y, wrB[1], biasB));
            float q1 = fmaf(a0.z, wrB[2], a0.w * wrB[3]);
            float q2 = fmaf(a1.x, wrB[4], a1.y * wrB[5]);
            float q3 = fmaf(a1.z, wrB[6], a1.w * wrB[7]);
            float q4 = fmaf(a2.x, wrB[8], a2.y * wrB[9]);
            float q5 = fmaf(a2.z, wrB[10], a2.w * wrB[11]);
            float q6 = fmaf(a3.x, wrB[12], a3.y * wrB[13]);
            float q7 = fmaf(a3.z, wrB[14], a3.w * wrB[15]);
            const float dotB = ((q0 + q1) + (q2 + q3)) + ((q4 + q5) + (q6 + q7));
            accA += fmaxf(hv.x + dotA, 0.f);
            accB += fmaxf(hv.y + dotB, 0.f);
        }
    }
    const float2 self = *(const float2*)(h + (size_t)node * 128 + dA);
    *(float2*)(out + (size_t)node * 128 + dA) =
        make_float2(self.x + accA, self.y + accB);
}

// ========================= Dense GEMM (node MLP) ============================
// OUT[n][j] = act( sum_k H[n][k]*W[j][k] + b[j] )
// In-place safe (H==OUT): each block reads only rows [base, base+NT) into LDS
// before writing the same rows; blocks own disjoint row ranges (clamp row
// N_NODES-1 belongs to the last block itself).
#define NT 128

template<int KIN, int JOUT, bool RELU>
__global__ __launch_bounds__(256) void k_mlp(
    const float* __restrict__ H, const float* __restrict__ W,
    const float* __restrict__ b, float* __restrict__ OUT)
{
    extern __shared__ float lds[];
    float* Wt = lds;                       // [KIN][128]
    float* hN = Wt + KIN * 128;            // [NT][KIN+4]
    const int HS = KIN + 4;

    const int tid  = threadIdx.x;
    const int nq   = tid & 7;
    const int jq   = (tid >> 3) & 15;
    const int half = tid >> 7;
    const int j0   = jq * 8;

    for (int idx = tid; idx < 128 * KIN; idx += 256) {
        const int j = idx / KIN, k = idx % KIN;
        Wt[k * 128 + j] = (j < JOUT) ? W[idx] : 0.f;
    }
    float bj[8];
#pragma unroll
    for (int m = 0; m < 8; ++m)
        bj[m] = (j0 + m < JOUT) ? b[j0 + m] : 0.f;
    __syncthreads();

    const int base = blockIdx.x * NT;

    for (int idx = tid; idx < NT * (KIN / 4); idx += 256) {
        const int kq = idx & (KIN / 4 - 1);
        const int n  = idx / (KIN / 4);
        const int ng = (base + n < N_NODES) ? (base + n) : (N_NODES - 1);
        *(float4*)(hN + n * HS + 4 * kq) =
            *(const float4*)(H + (size_t)ng * KIN + 4 * kq);
    }
    __syncthreads();

    int hoff[8];
#pragma unroll
    for (int i = 0; i < 8; ++i)
        hoff[i] = (64 * half + nq + 8 * i) * HS;

    float acc[8][8];
#pragma unroll
    for (int i = 0; i < 8; ++i)
#pragma unroll
        for (int m = 0; m < 8; ++m) acc[i][m] = 0.f;

#pragma unroll 4
    for (int k = 0; k < KIN; ++k) {
        const float4 wA = *(const float4*)(Wt + k * 128 + j0);
        const float4 wB = *(const float4*)(Wt + k * 128 + j0 + 4);
        float hv[8];
#pragma unroll
        for (int i = 0; i < 8; ++i) hv[i] = hN[hoff[i] + k];
#pragma unroll
        for (int i = 0; i < 8; ++i) {
            acc[i][0] = fmaf(hv[i], wA.x, acc[i][0]);
            acc[i][1] = fmaf(hv[i], wA.y, acc[i][1]);
            acc[i][2] = fmaf(hv[i], wA.z, acc[i][2]);
            acc[i][3] = fmaf(hv[i], wA.w, acc[i][3]);
            acc[i][4] = fmaf(hv[i], wB.x, acc[i][4]);
            acc[i][5] = fmaf(hv[i], wB.y, acc[i][5]);
            acc[i][6] = fmaf(hv[i], wB.z, acc[i][6]);
            acc[i][7] = fmaf(hv[i], wB.w, acc[i][7]);
        }
    }

#pragma unroll
    for (int i = 0; i < 8; ++i) {
        const int n = base + 64 * half + nq + 8 * i;
        if (n >= N_NODES) continue;
        float v[8];
#pragma unroll
        for (int m = 0; m < 8; ++m) {
            float t = acc[i][m] + bj[m];
            v[m] = RELU ? fmaxf(t, 0.f) : t;
        }
        float* row = OUT + (size_t)n * JOUT;
        if (JOUT == 128) {
            *(float4*)(row + j0)     = make_float4(v[0], v[1], v[2], v[3]);
            *(float4*)(row + j0 + 4) = make_float4(v[4], v[5], v[6], v[7]);
        } else {
#pragma unroll
            for (int m = 0; m < 8; ++m)
                if (j0 + m < JOUT) row[j0 + m] = v[m];
        }
    }
}

// ============================================================================
// Workspace layout (peak 105,804,800 B), lifetimes packed:
//   [0,        204800)  rowptr            (build .. edge2)
//   [204800,  3404800)  srcs              (prep .. edge2)
//       cnt    @204800  (hist..scan, dead before srcs written)
//       cursor @409600  (scan..scatter, dead before srcs written)
//   [3404800, 54604800) eaw  51.2MB       (prep .. edge2)
//   [54604800,80204800) t1 (=h1) 25.6MB   (mlp11 .. edge2-in)
//       pairs @54604800 6.4MB             (scatter..prep, dead before t1)
//   [80204800,105804800) h2pre 25.6MB     (edge2-out .. head, in-place MLPs)
//       h1pre @80204800 12.8MB            (edge1..mlp11, dead before h2pre)
extern "C" void kernel_launch(void* const* d_in, const int* in_sizes, int n_in,
                              void* d_out, int out_size, void* d_ws, size_t ws_size,
                              hipStream_t stream) {
    const float* x     = (const float*)d_in[0];
    const int*   ei    = (const int*)  d_in[1];
    const float* eattr = (const float*)d_in[2];
    const float* ew    = (const float*)d_in[3];
    const float* We1   = (const float*)d_in[4];
    const float* be1   = (const float*)d_in[5];
    const float* W11   = (const float*)d_in[6];
    const float* b11   = (const float*)d_in[7];
    const float* W12   = (const float*)d_in[8];
    const float* b12   = (const float*)d_in[9];
    const float* We2   = (const float*)d_in[10];
    const float* be2   = (const float*)d_in[11];
    const float* W21   = (const float*)d_in[12];
    const float* b21   = (const float*)d_in[13];
    const float* W22   = (const float*)d_in[14];
    const float* b22   = (const float*)d_in[15];
    const float* Wo    = (const float*)d_in[16];
    const float* bo    = (const float*)d_in[17];
    float* out = (float*)d_out;

    char* ws = (char*)d_ws;
    int*   rowptr = (int*)  (ws + 0);
    int*   cnt    = (int*)  (ws + 204800);
    int*   cursor = (int*)  (ws + 409600);
    int*   srcs   = (int*)  (ws + 204800);     // overlays cnt+cursor (dead)
    float* eaw    = (float*)(ws + 3404800);    // 51.2 MB
    float* t1     = (float*)(ws + 54604800);   // 25.6 MB (h1 alias)
    int2*  pairs  = (int2*) (ws + 54604800);   // 6.4 MB, dead before t1 written
    float* h2pre  = (float*)(ws + 80204800);   // 25.6 MB
    float* h1pre  = (float*)(ws + 80204800);   // 12.8 MB, dead before h2pre

    hipMemsetAsync(cnt, 0, 200000, stream);

    const int EB = (E_EDGES + 255) / 256;      // 3125
    k_hist<<<EB, 256, 0, stream>>>(ei, cnt);
    k_scan<<<1, 1024, 0, stream>>>(cnt, rowptr, cursor);
    k_scatter<<<EB, 256, 0, stream>>>(ei, cursor, pairs);

    const int PB = (E_EDGES * 4 + 255) / 256;  // 12500
    k_prep<<<PB, 256, 0, stream>>>(pairs, eattr, ew, eaw, srcs);

    const int NB = (N_NODES + 3) / 4;          // 12500
    k_edge1<<<NB, 256, 0, stream>>>(rowptr, srcs, eaw, We1, be1, x, h1pre);

    const int TILES = (N_NODES + NT - 1) / NT;                       // 391
    const size_t lds64  = (size_t)(64 * 128 + NT * (64 + 4)) * 4;    //  67,584 B
    const size_t lds128 = (size_t)(128 * 128 + NT * (128 + 4)) * 4;  // 133,120 B

    k_mlp<64, 128, true><<<TILES, 256, lds64, stream>>>(h1pre, W11, b11, t1);
    k_mlp<128, 128, true><<<TILES, 256, lds128, stream>>>(t1, W12, b12, t1);

    k_edge2<<<NB, 256, 0, stream>>>(rowptr, srcs, eaw, We2, be2, t1, h2pre);

    k_mlp<128, 128, true><<<TILES, 256, lds128, stream>>>(h2pre, W21, b21, h2pre);
    k_mlp<128, 128, true><<<TILES, 256, lds128, stream>>>(h2pre, W22, b22, h2pre);
    k_mlp<128, 100, false><<<TILES, 256, lds128, stream>>>(h2pre, Wo, bo, out);
}

// Round 2
// 859.432 us; speedup vs baseline: 1.1405x; 1.1004x over previous
//
#include <hip/hip_runtime.h>

#define N_NODES 50000
#define E_EDGES 800000

__device__ __forceinline__ float __rlf(float v, int l) {
    return __int_as_float(__builtin_amdgcn_readlane(__float_as_int(v), l));
}

// ============================ CSR build =====================================
__global__ __launch_bounds__(256) void k_hist(
    const int* __restrict__ ei, int* __restrict__ cnt)
{
    const int e = blockIdx.x * 256 + threadIdx.x;
    if (e < E_EDGES) atomicAdd(&cnt[ei[E_EDGES + e]], 1);
}

// single block, 1024 threads: exclusive prefix over cnt -> rowptr, cursor
__global__ __launch_bounds__(1024) void k_scan(
    const int* __restrict__ cnt, int* __restrict__ rowptr, int* __restrict__ cursor)
{
    __shared__ int part[1024];
    const int tid = threadIdx.x;
    const int CH = 49;                      // 1024*49 >= 50000
    const int base = tid * CH;
    int sum = 0;
    for (int c = 0; c < CH; ++c) {
        const int i = base + c;
        if (i < N_NODES) sum += cnt[i];
    }
    part[tid] = sum;
    __syncthreads();
    for (int off = 1; off < 1024; off <<= 1) {
        int v = part[tid];
        int u = (tid >= off) ? part[tid - off] : 0;
        __syncthreads();
        part[tid] = v + u;
        __syncthreads();
    }
    int run = (tid > 0) ? part[tid - 1] : 0;
    for (int c = 0; c < CH; ++c) {
        const int i = base + c;
        if (i < N_NODES) {
            rowptr[i] = run;
            cursor[i] = run;
            run += cnt[i];
        }
    }
    if (tid == 1023) rowptr[N_NODES] = part[1023];
}

__global__ __launch_bounds__(256) void k_scatter(
    const int* __restrict__ ei, int* __restrict__ cursor, int2* __restrict__ pairs)
{
    const int e = blockIdx.x * 256 + threadIdx.x;
    if (e < E_EDGES) {
        const int dst = ei[E_EDGES + e];
        const int pos = atomicAdd(&cursor[dst], 1);
        pairs[pos] = make_int2(ei[e], e);
    }
}

// ============ CSR-order edge-attr pre-scale (kills gather deps) =============
// eaw[pos][k] = ew[eid] * eattr[eid][k]  (layer-independent), srcs[pos] = src.
__global__ __launch_bounds__(256) void k_prep(
    const int2* __restrict__ pairs, const float* __restrict__ eattr,
    const float* __restrict__ ew, float* __restrict__ eaw, int* __restrict__ srcs)
{
    const int t = blockIdx.x * 256 + threadIdx.x;
    const int pos = t >> 2;
    if (pos >= E_EDGES) return;
    const int q = t & 3;
    const int2 p = pairs[pos];
    if (q == 0) srcs[pos] = p.x;
    const float w = ew[p.y];
    const float4 a = *((const float4*)(eattr + (size_t)p.y * 16) + q);
    *((float4*)(eaw + (size_t)pos * 16) + q) =
        make_float4(a.x * w, a.y * w, a.z * w, a.w * w);
}

// ===================== Edge layer 1 (CSR gather, 16->64) ====================
// out[v][d] = x[v][d] + sum_{e: dst=v} relu( x[src][d] + (eaw_e . We1[d]) + be1[d] )
// Per 16-edge chunk: ONE coalesced float4/lane load holds the chunk's edge
// attrs (lane 4j+q owns quarter q of edge j); per edge the 16 values are
// broadcast via v_readlane into SGPRs -> zero vector-memory traffic in the
// inner loop except the (coalesced) x-row read. srcs chunk likewise broadcast.
__global__ __launch_bounds__(256, 4) void k_edge1(
    const int* __restrict__ rp, const int* __restrict__ srcs,
    const float* __restrict__ eaw,
    const float* __restrict__ We1, const float* __restrict__ be1,
    const float* __restrict__ x, float* __restrict__ out)
{
    const int lane = threadIdx.x & 63;
    const int node = blockIdx.x * 4 + (threadIdx.x >> 6);
    if (node >= N_NODES) return;

    float wr[16];
#pragma unroll
    for (int k = 0; k < 16; ++k) wr[k] = We1[lane * 16 + k];
    const float bias = be1[lane];

    const int beg = rp[node], end = rp[node + 1];
    float acc = 0.f;

    for (int c = beg; c < end; c += 16) {
        const int n = end - c < 16 ? end - c : 16;   // uniform per wave
        const int li = c + (lane & 15);
        const int sl = srcs[li < end ? li : end - 1];   // coalesced (64B)
        const float4 ev = *(const float4*)(eaw + (size_t)c * 16 + lane * 4); // 1KB/wave
#pragma unroll 8
        for (int j = 0; j < n; ++j) {
            const int src = __builtin_amdgcn_readlane(sl, j);
            const float hv = x[(size_t)src * 64 + lane];   // coalesced row read
            const int L = 4 * j;
            const float e0  = __rlf(ev.x, L),     e1  = __rlf(ev.y, L);
            const float e2  = __rlf(ev.z, L),     e3  = __rlf(ev.w, L);
            const float e4  = __rlf(ev.x, L + 1), e5  = __rlf(ev.y, L + 1);
            const float e6  = __rlf(ev.z, L + 1), e7  = __rlf(ev.w, L + 1);
            const float e8  = __rlf(ev.x, L + 2), e9  = __rlf(ev.y, L + 2);
            const float e10 = __rlf(ev.z, L + 2), e11 = __rlf(ev.w, L + 2);
            const float e12 = __rlf(ev.x, L + 3), e13 = __rlf(ev.y, L + 3);
            const float e14 = __rlf(ev.z, L + 3), e15 = __rlf(ev.w, L + 3);
            float d0 = fmaf(e0,  wr[0],  fmaf(e1, wr[1], bias));
            float d1 = fmaf(e2,  wr[2],  e3  * wr[3]);
            float d2 = fmaf(e4,  wr[4],  e5  * wr[5]);
            float d3 = fmaf(e6,  wr[6],  e7  * wr[7]);
            float d4 = fmaf(e8,  wr[8],  e9  * wr[9]);
            float d5 = fmaf(e10, wr[10], e11 * wr[11]);
            float d6 = fmaf(e12, wr[12], e13 * wr[13]);
            float d7 = fmaf(e14, wr[14], e15 * wr[15]);
            const float dot = ((d0 + d1) + (d2 + d3)) + ((d4 + d5) + (d6 + d7));
            acc += fmaxf(hv + dot, 0.f);
        }
    }
    out[(size_t)node * 64 + lane] = x[(size_t)node * 64 + lane] + acc;
}

// ===================== Edge layer 2 (CSR gather, 16->128) ===================
// Lane owns dims (2*lane, 2*lane+1); same chunk-broadcast scheme; the 16
// SGPR-broadcast edge values feed BOTH dot trees.
__global__ __launch_bounds__(256, 4) void k_edge2(
    const int* __restrict__ rp, const int* __restrict__ srcs,
    const float* __restrict__ eaw,
    const float* __restrict__ We2, const float* __restrict__ be2,
    const float* __restrict__ h, float* __restrict__ out)
{
    const int lane = threadIdx.x & 63;
    const int node = blockIdx.x * 4 + (threadIdx.x >> 6);
    if (node >= N_NODES) return;

    const int dA = 2 * lane;
    float wrA[16], wrB[16];
#pragma unroll
    for (int k = 0; k < 16; ++k) wrA[k] = We2[dA * 16 + k];
#pragma unroll
    for (int k = 0; k < 16; ++k) wrB[k] = We2[(dA + 1) * 16 + k];
    const float biasA = be2[dA];
    const float biasB = be2[dA + 1];

    const int beg = rp[node], end = rp[node + 1];
    float accA = 0.f, accB = 0.f;

    for (int c = beg; c < end; c += 16) {
        const int n = end - c < 16 ? end - c : 16;
        const int li = c + (lane & 15);
        const int sl = srcs[li < end ? li : end - 1];
        const float4 ev = *(const float4*)(eaw + (size_t)c * 16 + lane * 4);
#pragma unroll 4
        for (int j = 0; j < n; ++j) {
            const int src = __builtin_amdgcn_readlane(sl, j);
            const float2 hv = *(const float2*)(h + (size_t)src * 128 + dA);
            const int L = 4 * j;
            const float e0  = __rlf(ev.x, L),     e1  = __rlf(ev.y, L);
            const float e2  = __rlf(ev.z, L),     e3  = __rlf(ev.w, L);
            const float e4  = __rlf(ev.x, L + 1), e5  = __rlf(ev.y, L + 1);
            const float e6  = __rlf(ev.z, L + 1), e7  = __rlf(ev.w, L + 1);
            const float e8  = __rlf(ev.x, L + 2), e9  = __rlf(ev.y, L + 2);
            const float e10 = __rlf(ev.z, L + 2), e11 = __rlf(ev.w, L + 2);
            const float e12 = __rlf(ev.x, L + 3), e13 = __rlf(ev.y, L + 3);
            const float e14 = __rlf(ev.z, L + 3), e15 = __rlf(ev.w, L + 3);
            float p0 = fmaf(e0,  wrA[0],  fmaf(e1, wrA[1], biasA));
            float p1 = fmaf(e2,  wrA[2],  e3  * wrA[3]);
            float p2 = fmaf(e4,  wrA[4],  e5  * wrA[5]);
            float p3 = fmaf(e6,  wrA[6],  e7  * wrA[7]);
            float p4 = fmaf(e8,  wrA[8],  e9  * wrA[9]);
            float p5 = fmaf(e10, wrA[10], e11 * wrA[11]);
            float p6 = fmaf(e12, wrA[12], e13 * wrA[13]);
            float p7 = fmaf(e14, wrA[14], e15 * wrA[15]);
            const float dotA = ((p0 + p1) + (p2 + p3)) + ((p4 + p5) + (p6 + p7));
            float q0 = fmaf(e0,  wrB[0],  fmaf(e1, wrB[1], biasB));
            float q1 = fmaf(e2,  wrB[2],  e3  * wrB[3]);
            float q2 = fmaf(e4,  wrB[4],  e5  * wrB[5]);
            float q3 = fmaf(e6,  wrB[6],  e7  * wrB[7]);
            float q4 = fmaf(e8,  wrB[8],  e9  * wrB[9]);
            float q5 = fmaf(e10, wrB[10], e11 * wrB[11]);
            float q6 = fmaf(e12, wrB[12], e13 * wrB[13]);
            float q7 = fmaf(e14, wrB[14], e15 * wrB[15]);
            const float dotB = ((q0 + q1) + (q2 + q3)) + ((q4 + q5) + (q6 + q7));
            accA += fmaxf(hv.x + dotA, 0.f);
            accB += fmaxf(hv.y + dotB, 0.f);
        }
    }
    const float2 self = *(const float2*)(h + (size_t)node * 128 + dA);
    *(float2*)(out + (size_t)node * 128 + dA) =
        make_float2(self.x + accA, self.y + accB);
}

// ========================= Dense GEMM (node MLP) ============================
// OUT[n][j] = act( sum_k H[n][k]*W[j][k] + b[j] )
// In-place safe (H==OUT): each block reads only rows [base, base+NT) into LDS
// before writing the same rows.
#define NT 128

template<int KIN, int JOUT, bool RELU>
__global__ __launch_bounds__(256) void k_mlp(
    const float* __restrict__ H, const float* __restrict__ W,
    const float* __restrict__ b, float* __restrict__ OUT)
{
    extern __shared__ float lds[];
    float* Wt = lds;                       // [KIN][128]
    float* hN = Wt + KIN * 128;            // [NT][KIN+4]
    const int HS = KIN + 4;

    const int tid  = threadIdx.x;
    const int nq   = tid & 7;
    const int jq   = (tid >> 3) & 15;
    const int half = tid >> 7;
    const int j0   = jq * 8;

    for (int idx = tid; idx < 128 * KIN; idx += 256) {
        const int j = idx / KIN, k = idx % KIN;
        Wt[k * 128 + j] = (j < JOUT) ? W[idx] : 0.f;
    }
    float bj[8];
#pragma unroll
    for (int m = 0; m < 8; ++m)
        bj[m] = (j0 + m < JOUT) ? b[j0 + m] : 0.f;
    __syncthreads();

    const int base = blockIdx.x * NT;

    for (int idx = tid; idx < NT * (KIN / 4); idx += 256) {
        const int kq = idx & (KIN / 4 - 1);
        const int n  = idx / (KIN / 4);
        const int ng = (base + n < N_NODES) ? (base + n) : (N_NODES - 1);
        *(float4*)(hN + n * HS + 4 * kq) =
            *(const float4*)(H + (size_t)ng * KIN + 4 * kq);
    }
    __syncthreads();

    int hoff[8];
#pragma unroll
    for (int i = 0; i < 8; ++i)
        hoff[i] = (64 * half + nq + 8 * i) * HS;

    float acc[8][8];
#pragma unroll
    for (int i = 0; i < 8; ++i)
#pragma unroll
        for (int m = 0; m < 8; ++m) acc[i][m] = 0.f;

#pragma unroll 4
    for (int k = 0; k < KIN; ++k) {
        const float4 wA = *(const float4*)(Wt + k * 128 + j0);
        const float4 wB = *(const float4*)(Wt + k * 128 + j0 + 4);
        float hv[8];
#pragma unroll
        for (int i = 0; i < 8; ++i) hv[i] = hN[hoff[i] + k];
#pragma unroll
        for (int i = 0; i < 8; ++i) {
            acc[i][0] = fmaf(hv[i], wA.x, acc[i][0]);
            acc[i][1] = fmaf(hv[i], wA.y, acc[i][1]);
            acc[i][2] = fmaf(hv[i], wA.z, acc[i][2]);
            acc[i][3] = fmaf(hv[i], wA.w, acc[i][3]);
            acc[i][4] = fmaf(hv[i], wB.x, acc[i][4]);
            acc[i][5] = fmaf(hv[i], wB.y, acc[i][5]);
            acc[i][6] = fmaf(hv[i], wB.z, acc[i][6]);
            acc[i][7] = fmaf(hv[i], wB.w, acc[i][7]);
        }
    }

#pragma unroll
    for (int i = 0; i < 8; ++i) {
        const int n = base + 64 * half + nq + 8 * i;
        if (n >= N_NODES) continue;
        float v[8];
#pragma unroll
        for (int m = 0; m < 8; ++m) {
            float t = acc[i][m] + bj[m];
            v[m] = RELU ? fmaxf(t, 0.f) : t;
        }
        float* row = OUT + (size_t)n * JOUT;
        if (JOUT == 128) {
            *(float4*)(row + j0)     = make_float4(v[0], v[1], v[2], v[3]);
            *(float4*)(row + j0 + 4) = make_float4(v[4], v[5], v[6], v[7]);
        } else {
#pragma unroll
            for (int m = 0; m < 8; ++m)
                if (j0 + m < JOUT) row[j0 + m] = v[m];
        }
    }
}

// ============================================================================
// Workspace layout (peak 105,804,800 B), lifetimes packed:
//   [0,        204800)  rowptr            (build .. edge2)
//   [204800,  3404800)  srcs              (prep .. edge2)
//       cnt    @204800  (hist..scan, dead before srcs written)
//       cursor @409600  (scan..scatter, dead before srcs written)
//   [3404800, 54604800) eaw  51.2MB       (prep .. edge2)
//     NOTE: edge kernels may over-read up to 1KB past a row's end (chunk
//     granularity); bytes land in t1 region (allocated), values unused.
//   [54604800,80204800) t1 (=h1) 25.6MB   (mlp11 .. edge2-in)
//       pairs @54604800 6.4MB             (scatter..prep, dead before t1)
//   [80204800,105804800) h2pre 25.6MB     (edge2-out .. head, in-place MLPs)
//       h1pre @80204800 12.8MB            (edge1..mlp11, dead before h2pre)
extern "C" void kernel_launch(void* const* d_in, const int* in_sizes, int n_in,
                              void* d_out, int out_size, void* d_ws, size_t ws_size,
                              hipStream_t stream) {
    const float* x     = (const float*)d_in[0];
    const int*   ei    = (const int*)  d_in[1];
    const float* eattr = (const float*)d_in[2];
    const float* ew    = (const float*)d_in[3];
    const float* We1   = (const float*)d_in[4];
    const float* be1   = (const float*)d_in[5];
    const float* W11   = (const float*)d_in[6];
    const float* b11   = (const float*)d_in[7];
    const float* W12   = (const float*)d_in[8];
    const float* b12   = (const float*)d_in[9];
    const float* We2   = (const float*)d_in[10];
    const float* be2   = (const float*)d_in[11];
    const float* W21   = (const float*)d_in[12];
    const float* b21   = (const float*)d_in[13];
    const float* W22   = (const float*)d_in[14];
    const float* b22   = (const float*)d_in[15];
    const float* Wo    = (const float*)d_in[16];
    const float* bo    = (const float*)d_in[17];
    float* out = (float*)d_out;

    char* ws = (char*)d_ws;
    int*   rowptr = (int*)  (ws + 0);
    int*   cnt    = (int*)  (ws + 204800);
    int*   cursor = (int*)  (ws + 409600);
    int*   srcs   = (int*)  (ws + 204800);     // overlays cnt+cursor (dead)
    float* eaw    = (float*)(ws + 3404800);    // 51.2 MB
    float* t1     = (float*)(ws + 54604800);   // 25.6 MB (h1 alias)
    int2*  pairs  = (int2*) (ws + 54604800);   // 6.4 MB, dead before t1 written
    float* h2pre  = (float*)(ws + 80204800);   // 25.6 MB
    float* h1pre  = (float*)(ws + 80204800);   // 12.8 MB, dead before h2pre

    hipMemsetAsync(cnt, 0, 200000, stream);

    const int EB = (E_EDGES + 255) / 256;      // 3125
    k_hist<<<EB, 256, 0, stream>>>(ei, cnt);
    k_scan<<<1, 1024, 0, stream>>>(cnt, rowptr, cursor);
    k_scatter<<<EB, 256, 0, stream>>>(ei, cursor, pairs);

    const int PB = (E_EDGES * 4 + 255) / 256;  // 12500
    k_prep<<<PB, 256, 0, stream>>>(pairs, eattr, ew, eaw, srcs);

    const int NB = (N_NODES + 3) / 4;          // 12500
    k_edge1<<<NB, 256, 0, stream>>>(rowptr, srcs, eaw, We1, be1, x, h1pre);

    const int TILES = (N_NODES + NT - 1) / NT;                       // 391
    const size_t lds64  = (size_t)(64 * 128 + NT * (64 + 4)) * 4;    //  67,584 B
    const size_t lds128 = (size_t)(128 * 128 + NT * (128 + 4)) * 4;  // 133,120 B

    k_mlp<64, 128, true><<<TILES, 256, lds64, stream>>>(h1pre, W11, b11, t1);
    k_mlp<128, 128, true><<<TILES, 256, lds128, stream>>>(t1, W12, b12, t1);

    k_edge2<<<NB, 256, 0, stream>>>(rowptr, srcs, eaw, We2, be2, t1, h2pre);

    k_mlp<128, 128, true><<<TILES, 256, lds128, stream>>>(h2pre, W21, b21, h2pre);
    k_mlp<128, 128, true><<<TILES, 256, lds128, stream>>>(h2pre, W22, b22, h2pre);
    k_mlp<128, 100, false><<<TILES, 256, lds128, stream>>>(h2pre, Wo, bo, out);
}

// Round 3
// 743.500 us; speedup vs baseline: 1.3184x; 1.1559x over previous
//
#include <hip/hip_runtime.h>

#define N_NODES 50000
#define E_EDGES 800000

__device__ __forceinline__ float __rlf(float v, int l) {
    return __int_as_float(__builtin_amdgcn_readlane(__float_as_int(v), l));
}

// ============================ CSR build =====================================
__global__ __launch_bounds__(256) void k_hist(
    const int* __restrict__ ei, int* __restrict__ cnt)
{
    const int e = blockIdx.x * 256 + threadIdx.x;
    if (e < E_EDGES) atomicAdd(&cnt[ei[E_EDGES + e]], 1);
}

// single block, 1024 threads: exclusive prefix over cnt -> rowptr, cursor
__global__ __launch_bounds__(1024) void k_scan(
    const int* __restrict__ cnt, int* __restrict__ rowptr, int* __restrict__ cursor)
{
    __shared__ int part[1024];
    const int tid = threadIdx.x;
    const int CH = 49;                      // 1024*49 >= 50000
    const int base = tid * CH;
    int sum = 0;
    for (int c = 0; c < CH; ++c) {
        const int i = base + c;
        if (i < N_NODES) sum += cnt[i];
    }
    part[tid] = sum;
    __syncthreads();
    for (int off = 1; off < 1024; off <<= 1) {
        int v = part[tid];
        int u = (tid >= off) ? part[tid - off] : 0;
        __syncthreads();
        part[tid] = v + u;
        __syncthreads();
    }
    int run = (tid > 0) ? part[tid - 1] : 0;
    for (int c = 0; c < CH; ++c) {
        const int i = base + c;
        if (i < N_NODES) {
            rowptr[i] = run;
            cursor[i] = run;
            run += cnt[i];
        }
    }
    if (tid == 1023) rowptr[N_NODES] = part[1023];
}

__global__ __launch_bounds__(256) void k_scatter(
    const int* __restrict__ ei, int* __restrict__ cursor, int2* __restrict__ pairs)
{
    const int e = blockIdx.x * 256 + threadIdx.x;
    if (e < E_EDGES) {
        const int dst = ei[E_EDGES + e];
        const int pos = atomicAdd(&cursor[dst], 1);
        pairs[pos] = make_int2(ei[e], e);
    }
}

// ============ CSR-order edge-attr pre-scale (kills gather deps) =============
__global__ __launch_bounds__(256) void k_prep(
    const int2* __restrict__ pairs, const float* __restrict__ eattr,
    const float* __restrict__ ew, float* __restrict__ eaw, int* __restrict__ srcs)
{
    const int t = blockIdx.x * 256 + threadIdx.x;
    const int pos = t >> 2;
    if (pos >= E_EDGES) return;
    const int q = t & 3;
    const int2 p = pairs[pos];
    if (q == 0) srcs[pos] = p.x;
    const float w = ew[p.y];
    const float4 a = *((const float4*)(eattr + (size_t)p.y * 16) + q);
    *((float4*)(eaw + (size_t)pos * 16) + q) =
        make_float4(a.x * w, a.y * w, a.z * w, a.w * w);
}

// ================== Weight transpose for MLP (once, tiny) ==================
// WT segments (float offsets): WT11@0 [64][128], WT12@8192 [128][128],
// WT21@24576, WT22@40960, WTo@57344 [128][128] (j>=100 zero-padded).
__global__ __launch_bounds__(256) void k_wt(
    const float* __restrict__ W11, const float* __restrict__ W12,
    const float* __restrict__ W21, const float* __restrict__ W22,
    const float* __restrict__ Wo, float* __restrict__ WT)
{
    const int bid = blockIdx.x;
    const float* src; int KIN, JOUT, lbase, obase;
    if (bid < 32)       { src = W11; KIN = 64;  JOUT = 128; lbase = 0;   obase = 0; }
    else if (bid < 96)  { src = W12; KIN = 128; JOUT = 128; lbase = 32;  obase = 8192; }
    else if (bid < 160) { src = W21; KIN = 128; JOUT = 128; lbase = 96;  obase = 24576; }
    else if (bid < 224) { src = W22; KIN = 128; JOUT = 128; lbase = 160; obase = 40960; }
    else                { src = Wo;  KIN = 128; JOUT = 100; lbase = 224; obase = 57344; }
    const int idx = (bid - lbase) * 256 + threadIdx.x;   // < KIN*128
    const int k = idx >> 7, j = idx & 127;
    WT[obase + idx] = (j < JOUT) ? src[j * KIN + k] : 0.f;
}

// ===================== Edge layer 1 (CSR gather, 16->64) ====================
// Chunk-broadcast (1 coalesced float4/lane per 16 edges, readlane -> SGPR),
// chained-FMA dot (bias-seeded, no tree adds), next-chunk prefetch.
__global__ __launch_bounds__(256, 4) void k_edge1(
    const int* __restrict__ rp, const int* __restrict__ srcs,
    const float* __restrict__ eaw,
    const float* __restrict__ We1, const float* __restrict__ be1,
    const float* __restrict__ x, float* __restrict__ out)
{
    const int lane = threadIdx.x & 63;
    const int node = blockIdx.x * 4 + (threadIdx.x >> 6);
    if (node >= N_NODES) return;

    float wr[16];
#pragma unroll
    for (int k = 0; k < 16; ++k) wr[k] = We1[lane * 16 + k];
    const float bias = be1[lane];

    const int beg = rp[node], end = rp[node + 1];
    float acc = 0.f;

    if (beg < end) {
        int l16 = beg + (lane & 15);
        int sl = srcs[l16 < end ? l16 : end - 1];
        float4 ev = *(const float4*)(eaw + (size_t)beg * 16 + lane * 4);
        for (int c = beg; c < end; c += 16) {
            const int cp = (c + 16 < end) ? c + 16 : c;      // prefetch chunk
            const int lp = cp + (lane & 15);
            const int sln = srcs[lp < end ? lp : end - 1];
            const float4 evn = *(const float4*)(eaw + (size_t)cp * 16 + lane * 4);
            const int n = end - c < 16 ? end - c : 16;       // uniform per wave
#pragma unroll 8
            for (int j = 0; j < n; ++j) {
                const int src = __builtin_amdgcn_readlane(sl, j);
                const float hv = x[(size_t)src * 64 + lane];
                const int L = 4 * j;
                float d = bias;
                d = fmaf(__rlf(ev.x, L),     wr[0],  d);
                d = fmaf(__rlf(ev.y, L),     wr[1],  d);
                d = fmaf(__rlf(ev.z, L),     wr[2],  d);
                d = fmaf(__rlf(ev.w, L),     wr[3],  d);
                d = fmaf(__rlf(ev.x, L + 1), wr[4],  d);
                d = fmaf(__rlf(ev.y, L + 1), wr[5],  d);
                d = fmaf(__rlf(ev.z, L + 1), wr[6],  d);
                d = fmaf(__rlf(ev.w, L + 1), wr[7],  d);
                d = fmaf(__rlf(ev.x, L + 2), wr[8],  d);
                d = fmaf(__rlf(ev.y, L + 2), wr[9],  d);
                d = fmaf(__rlf(ev.z, L + 2), wr[10], d);
                d = fmaf(__rlf(ev.w, L + 2), wr[11], d);
                d = fmaf(__rlf(ev.x, L + 3), wr[12], d);
                d = fmaf(__rlf(ev.y, L + 3), wr[13], d);
                d = fmaf(__rlf(ev.z, L + 3), wr[14], d);
                d = fmaf(__rlf(ev.w, L + 3), wr[15], d);
                acc += fmaxf(hv + d, 0.f);
            }
            sl = sln; ev = evn;
        }
    }
    out[(size_t)node * 64 + lane] = x[(size_t)node * 64 + lane] + acc;
}

// ===================== Edge layer 2 (CSR gather, 16->128) ===================
__global__ __launch_bounds__(256, 4) void k_edge2(
    const int* __restrict__ rp, const int* __restrict__ srcs,
    const float* __restrict__ eaw,
    const float* __restrict__ We2, const float* __restrict__ be2,
    const float* __restrict__ h, float* __restrict__ out)
{
    const int lane = threadIdx.x & 63;
    const int node = blockIdx.x * 4 + (threadIdx.x >> 6);
    if (node >= N_NODES) return;

    const int dA = 2 * lane;
    float wrA[16], wrB[16];
#pragma unroll
    for (int k = 0; k < 16; ++k) wrA[k] = We2[dA * 16 + k];
#pragma unroll
    for (int k = 0; k < 16; ++k) wrB[k] = We2[(dA + 1) * 16 + k];
    const float biasA = be2[dA];
    const float biasB = be2[dA + 1];

    const int beg = rp[node], end = rp[node + 1];
    float accA = 0.f, accB = 0.f;

    if (beg < end) {
        int l16 = beg + (lane & 15);
        int sl = srcs[l16 < end ? l16 : end - 1];
        float4 ev = *(const float4*)(eaw + (size_t)beg * 16 + lane * 4);
        for (int c = beg; c < end; c += 16) {
            const int cp = (c + 16 < end) ? c + 16 : c;
            const int lp = cp + (lane & 15);
            const int sln = srcs[lp < end ? lp : end - 1];
            const float4 evn = *(const float4*)(eaw + (size_t)cp * 16 + lane * 4);
            const int n = end - c < 16 ? end - c : 16;
#pragma unroll 4
            for (int j = 0; j < n; ++j) {
                const int src = __builtin_amdgcn_readlane(sl, j);
                const float2 hv = *(const float2*)(h + (size_t)src * 128 + dA);
                const int L = 4 * j;
                const float e0  = __rlf(ev.x, L),     e1  = __rlf(ev.y, L);
                const float e2  = __rlf(ev.z, L),     e3  = __rlf(ev.w, L);
                const float e4  = __rlf(ev.x, L + 1), e5  = __rlf(ev.y, L + 1);
                const float e6  = __rlf(ev.z, L + 1), e7  = __rlf(ev.w, L + 1);
                const float e8  = __rlf(ev.x, L + 2), e9  = __rlf(ev.y, L + 2);
                const float e10 = __rlf(ev.z, L + 2), e11 = __rlf(ev.w, L + 2);
                const float e12 = __rlf(ev.x, L + 3), e13 = __rlf(ev.y, L + 3);
                const float e14 = __rlf(ev.z, L + 3), e15 = __rlf(ev.w, L + 3);
                float dA_ = biasA;
                dA_ = fmaf(e0,  wrA[0],  dA_); dA_ = fmaf(e1,  wrA[1],  dA_);
                dA_ = fmaf(e2,  wrA[2],  dA_); dA_ = fmaf(e3,  wrA[3],  dA_);
                dA_ = fmaf(e4,  wrA[4],  dA_); dA_ = fmaf(e5,  wrA[5],  dA_);
                dA_ = fmaf(e6,  wrA[6],  dA_); dA_ = fmaf(e7,  wrA[7],  dA_);
                dA_ = fmaf(e8,  wrA[8],  dA_); dA_ = fmaf(e9,  wrA[9],  dA_);
                dA_ = fmaf(e10, wrA[10], dA_); dA_ = fmaf(e11, wrA[11], dA_);
                dA_ = fmaf(e12, wrA[12], dA_); dA_ = fmaf(e13, wrA[13], dA_);
                dA_ = fmaf(e14, wrA[14], dA_); dA_ = fmaf(e15, wrA[15], dA_);
                float dB_ = biasB;
                dB_ = fmaf(e0,  wrB[0],  dB_); dB_ = fmaf(e1,  wrB[1],  dB_);
                dB_ = fmaf(e2,  wrB[2],  dB_); dB_ = fmaf(e3,  wrB[3],  dB_);
                dB_ = fmaf(e4,  wrB[4],  dB_); dB_ = fmaf(e5,  wrB[5],  dB_);
                dB_ = fmaf(e6,  wrB[6],  dB_); dB_ = fmaf(e7,  wrB[7],  dB_);
                dB_ = fmaf(e8,  wrB[8],  dB_); dB_ = fmaf(e9,  wrB[9],  dB_);
                dB_ = fmaf(e10, wrB[10], dB_); dB_ = fmaf(e11, wrB[11], dB_);
                dB_ = fmaf(e12, wrB[12], dB_); dB_ = fmaf(e13, wrB[13], dB_);
                dB_ = fmaf(e14, wrB[14], dB_); dB_ = fmaf(e15, wrB[15], dB_);
                accA += fmaxf(hv.x + dA_, 0.f);
                accB += fmaxf(hv.y + dB_, 0.f);
            }
            sl = sln; ev = evn;
        }
    }
    const float2 self = *(const float2*)(h + (size_t)node * 128 + dA);
    *(float2*)(out + (size_t)node * 128 + dA) =
        make_float2(self.x + accA, self.y + accB);
}

// ========================= Dense GEMM (node MLP) ============================
// OUT[n][j] = act( sum_k H[n][k]*WT[k][j] + b[j] ),  WT pre-transposed.
// Wave wv owns j = 32*wv..32*wv+31 (WAVE-UNIFORM -> W row via s_load/SGPR);
// lane owns nodes (lane, lane+64). LDS holds ONLY the transposed H tile
// hT[k][129] (66 KB @KIN=128 -> 2 blocks/CU; was 133 KB -> 1 block/CU).
// Per k: 1 ds_read2_b32 (conflict-free, pad 129) + 64 FMA (SGPR x VGPR).
// In-place safe (H==OUT): block reads only rows [base, base+NT) (clamp row
// N_NODES-1 belongs to the last block itself) before writing the same rows.
#define NT 128

template<int KIN, int JOUT, bool RELU>
__global__ __launch_bounds__(256) void k_mlp(
    const float* __restrict__ H, const float* __restrict__ WT,
    const float* __restrict__ b, float* __restrict__ OUT)
{
    extern __shared__ float hT[];          // [KIN][129]
    const int tid  = threadIdx.x;
    const int lane = tid & 63;
    const int wv   = __builtin_amdgcn_readfirstlane(tid >> 6);
    const int j0   = wv * 32;
    const int base = blockIdx.x * NT;

    // stage H tile TRANSPOSED: hT[k][n], pad 129 (write 4-way, read free)
    for (int idx = tid; idx < NT * (KIN / 4); idx += 256) {
        const int q = idx & (KIN / 4 - 1);
        const int n = idx / (KIN / 4);
        const int ng = (base + n < N_NODES) ? (base + n) : (N_NODES - 1);
        const float4 v = *(const float4*)(H + (size_t)ng * KIN + 4 * q);
        hT[(4 * q + 0) * 129 + n] = v.x;
        hT[(4 * q + 1) * 129 + n] = v.y;
        hT[(4 * q + 2) * 129 + n] = v.z;
        hT[(4 * q + 3) * 129 + n] = v.w;
    }
    __syncthreads();

    float acc0[32], acc1[32];
#pragma unroll
    for (int m = 0; m < 32; ++m) { acc0[m] = 0.f; acc1[m] = 0.f; }

    // 1-deep prefetch: W row (SGPR via uniform load) + h pair (LDS)
    float wc[32];
#pragma unroll
    for (int m = 0; m < 32; ++m) wc[m] = WT[j0 + m];
    float h0 = hT[lane], h1 = hT[lane + 64];

    for (int k = 0; k < KIN - 1; ++k) {
        float wn[32];
#pragma unroll
        for (int m = 0; m < 32; ++m) wn[m] = WT[(k + 1) * 128 + j0 + m];
        const float h0n = hT[(k + 1) * 129 + lane];
        const float h1n = hT[(k + 1) * 129 + lane + 64];
#pragma unroll
        for (int m = 0; m < 32; ++m) {
            acc0[m] = fmaf(h0, wc[m], acc0[m]);
            acc1[m] = fmaf(h1, wc[m], acc1[m]);
        }
#pragma unroll
        for (int m = 0; m < 32; ++m) wc[m] = wn[m];
        h0 = h0n; h1 = h1n;
    }
#pragma unroll
    for (int m = 0; m < 32; ++m) {
        acc0[m] = fmaf(h0, wc[m], acc0[m]);
        acc1[m] = fmaf(h1, wc[m], acc1[m]);
    }

    float bv[32];
#pragma unroll
    for (int m = 0; m < 32; ++m) bv[m] = (j0 + m < JOUT) ? b[j0 + m] : 0.f;

    const int n0 = base + lane, n1 = base + lane + 64;
    if (n0 < N_NODES) {
        float* row = OUT + (size_t)n0 * JOUT;
#pragma unroll
        for (int g = 0; g < 8; ++g) {
            if (j0 + 4 * g < JOUT) {           // JOUT%4==0: full groups only
                float4 v;
                v.x = acc0[4 * g + 0] + bv[4 * g + 0];
                v.y = acc0[4 * g + 1] + bv[4 * g + 1];
                v.z = acc0[4 * g + 2] + bv[4 * g + 2];
                v.w = acc0[4 * g + 3] + bv[4 * g + 3];
                if (RELU) {
                    v.x = fmaxf(v.x, 0.f); v.y = fmaxf(v.y, 0.f);
                    v.z = fmaxf(v.z, 0.f); v.w = fmaxf(v.w, 0.f);
                }
                *(float4*)(row + j0 + 4 * g) = v;
            }
        }
    }
    if (n1 < N_NODES) {
        float* row = OUT + (size_t)n1 * JOUT;
#pragma unroll
        for (int g = 0; g < 8; ++g) {
            if (j0 + 4 * g < JOUT) {
                float4 v;
                v.x = acc1[4 * g + 0] + bv[4 * g + 0];
                v.y = acc1[4 * g + 1] + bv[4 * g + 1];
                v.z = acc1[4 * g + 2] + bv[4 * g + 2];
                v.w = acc1[4 * g + 3] + bv[4 * g + 3];
                if (RELU) {
                    v.x = fmaxf(v.x, 0.f); v.y = fmaxf(v.y, 0.f);
                    v.z = fmaxf(v.z, 0.f); v.w = fmaxf(v.w, 0.f);
                }
                *(float4*)(row + j0 + 4 * g) = v;
            }
        }
    }
}

// ============================================================================
// Workspace layout (peak 106,099,712 B), lifetimes packed:
//   [0,        204800)  rowptr            (build .. edge2)
//   [204800,  3404800)  srcs              (prep .. edge2)
//       cnt    @204800  (hist..scan, dead before srcs written)
//       cursor @409600  (scan..scatter, dead before srcs written)
//   [3404800, 54604800) eaw  51.2MB       (prep .. edge2)
//     NOTE: edge kernels may over-read up to 1KB past a row's end (chunk
//     granularity); bytes land in t1 region (allocated), values unused.
//   [54604800,80204800) t1 (=h1) 25.6MB   (mlp11 .. edge2-in)
//       pairs @54604800 6.4MB             (scatter..prep, dead before t1)
//   [80204800,105804800) h2pre 25.6MB     (edge2-out .. head, in-place MLPs)
//       h1pre @80204800 12.8MB            (edge1..mlp11, dead before h2pre)
//   [105804800,106099712) WT 294,912 B    (k_wt .. head)
extern "C" void kernel_launch(void* const* d_in, const int* in_sizes, int n_in,
                              void* d_out, int out_size, void* d_ws, size_t ws_size,
                              hipStream_t stream) {
    const float* x     = (const float*)d_in[0];
    const int*   ei    = (const int*)  d_in[1];
    const float* eattr = (const float*)d_in[2];
    const float* ew    = (const float*)d_in[3];
    const float* We1   = (const float*)d_in[4];
    const float* be1   = (const float*)d_in[5];
    const float* W11   = (const float*)d_in[6];
    const float* b11   = (const float*)d_in[7];
    const float* W12   = (const float*)d_in[8];
    const float* b12   = (const float*)d_in[9];
    const float* We2   = (const float*)d_in[10];
    const float* be2   = (const float*)d_in[11];
    const float* W21   = (const float*)d_in[12];
    const float* b21   = (const float*)d_in[13];
    const float* W22   = (const float*)d_in[14];
    const float* b22   = (const float*)d_in[15];
    const float* Wo    = (const float*)d_in[16];
    const float* bo    = (const float*)d_in[17];
    float* out = (float*)d_out;

    char* ws = (char*)d_ws;
    int*   rowptr = (int*)  (ws + 0);
    int*   cnt    = (int*)  (ws + 204800);
    int*   cursor = (int*)  (ws + 409600);
    int*   srcs   = (int*)  (ws + 204800);     // overlays cnt+cursor (dead)
    float* eaw    = (float*)(ws + 3404800);    // 51.2 MB
    float* t1     = (float*)(ws + 54604800);   // 25.6 MB (h1 alias)
    int2*  pairs  = (int2*) (ws + 54604800);   // 6.4 MB, dead before t1 written
    float* h2pre  = (float*)(ws + 80204800);   // 25.6 MB
    float* h1pre  = (float*)(ws + 80204800);   // 12.8 MB, dead before h2pre
    float* WT     = (float*)(ws + 105804800);  // 294,912 B
    float* WT11 = WT;          // [64][128]
    float* WT12 = WT + 8192;   // [128][128]
    float* WT21 = WT + 24576;
    float* WT22 = WT + 40960;
    float* WTo  = WT + 57344;  // [128][128] zero-padded j>=100

    hipMemsetAsync(cnt, 0, 200000, stream);

    k_wt<<<288, 256, 0, stream>>>(W11, W12, W21, W22, Wo, WT);

    const int EB = (E_EDGES + 255) / 256;      // 3125
    k_hist<<<EB, 256, 0, stream>>>(ei, cnt);
    k_scan<<<1, 1024, 0, stream>>>(cnt, rowptr, cursor);
    k_scatter<<<EB, 256, 0, stream>>>(ei, cursor, pairs);

    const int PB = (E_EDGES * 4 + 255) / 256;  // 12500
    k_prep<<<PB, 256, 0, stream>>>(pairs, eattr, ew, eaw, srcs);

    const int NB = (N_NODES + 3) / 4;          // 12500
    k_edge1<<<NB, 256, 0, stream>>>(rowptr, srcs, eaw, We1, be1, x, h1pre);

    const int TILES = (N_NODES + NT - 1) / NT;          // 391
    const size_t lds64  = (size_t)(64  * 129) * 4;      // 33,024 B
    const size_t lds128 = (size_t)(128 * 129) * 4;      // 66,048 B

    k_mlp<64, 128, true><<<TILES, 256, lds64, stream>>>(h1pre, WT11, b11, t1);
    k_mlp<128, 128, true><<<TILES, 256, lds128, stream>>>(t1, WT12, b12, t1);

    k_edge2<<<NB, 256, 0, stream>>>(rowptr, srcs, eaw, We2, be2, t1, h2pre);

    k_mlp<128, 128, true><<<TILES, 256, lds128, stream>>>(h2pre, WT21, b21, h2pre);
    k_mlp<128, 128, true><<<TILES, 256, lds128, stream>>>(h2pre, WT22, b22, h2pre);
    k_mlp<128, 100, false><<<TILES, 256, lds128, stream>>>(h2pre, WTo, bo, out);
}